// Round 3
// baseline (36867.673 us; speedup 1.0000x reference)
//
#include <hip/hip_runtime.h>
#include <hip/hip_bf16.h>
#include <cstdint>
#include <cstddef>

// ---------------------------------------------------------------------------
// 3-layer LSTM (AWD-LSTM encoder, eval), S=512 B=64 V=50000 E=400 H=1150.
// FP32 in/out; fp16 MFMA compute with fp32 accumulation.
//
// r8: merge L0 + L1-IH into one block (r7's cached-read+fence experiment
// REVERTED: fence serialized ~22 us/step and FETCH_SIZE proved no L2 reuse
// materialized; correctness only held by eviction luck). Observation: at
// step tau, L0 block g and IH block g read the IDENTICAL 147 KB (full
// h0_{tau-1}: L0's A for h@Whh0, IH's A for x1@Wih1 since x1_t = h0_t).
// Merged block g: Whh0 LDS-resident, Wih0 (53 KB) + Wih1-slice (147 KB)
// streamed from L2 (immutable), reads h0_{tau-1} ONCE via sc0sc1 bypass,
// computes gates0 -> h0_tau AND partial1 (t'=tau-1) -> write-through.
// Bypass-read volume drops 38 -> 27.4 MB/step (the measured ~1.0-1.2 TB/s
// effective bypass-read floor tracks volume). Grid: 72 merged + 72 HH +
// 25 L2 = 169 blocks, all co-resident. Lags unchanged (HH 2, L2 3; 515
// steps). Two extra in-block syncs serialize the two LDS gate-reduces.
// From r6: HH blocks (Whh1 LDS-resident, lag 2), contention-free tree
// barrier, 8-slot L3-resident h rings, fence-free sc0sc1 coherence,
// fragment-major LDS weights (0 bank conflicts), K-split waves,
// wave-shuffle-packed 16B h stores, sched_barrier(0) after asm waitcnts.
// ---------------------------------------------------------------------------

typedef _Float16 f16x8 __attribute__((ext_vector_type(8)));
typedef float f32x4 __attribute__((ext_vector_type(4)));
typedef unsigned int u32x4 __attribute__((ext_vector_type(4)));

#define LSTM_NBLK   169
#define LSTM_WSTEPS 515
#define LDS_W_HALFS (4 * 36 * 64 * 8)             // 73728 halves = 147456 B
#define LDS_TOTAL_BYTES (LDS_W_HALFS * 2 + 16384) // + 4x1024 fp32 gates = 163840
#define GO_BASE 176                               // go lines start at this slot

struct KParams {
  const unsigned short* res[3];   // resident W: Whh0, Whh1, Wih2 (frag-major, NKB=36)
  const unsigned short* strm[3];  // Wih0(13), Wih1(36), Whh2(13) frag-major
  const float* bias[3];           // bih+bhh fused [4][1152] fp32
  const unsigned short* xin0;     // gathered emb  [512][64][416] fp16 (immutable)
  unsigned short* ring[3];        // h rings [8][64][HSTR] fp16
  float* part;                    // L1 partial gates [2][72][1024][4] fp32
  float* out;                     // [512][64][400] fp32
  int* bar;                       // arrive[169] + go[8] flags, 128B-spaced
};

__device__ __forceinline__ float sigm_(float x) { return 1.0f / (1.0f + __expf(-x)); }
__device__ __forceinline__ float tanh_(float x) { return 2.0f * sigm_(2.0f * x) - 1.0f; }
__device__ __forceinline__ unsigned short f2h(float x) {
  _Float16 h = (_Float16)x;
  return __builtin_bit_cast(unsigned short, h);
}
// Device-coherent ops: bypass L1/L2, hit the coherence point.
__device__ __forceinline__ u32x4 load_sc(const unsigned short* p) {
  u32x4 r;
  asm volatile("global_load_dwordx4 %0, %1, off sc0 sc1"
               : "=v"(r) : "v"(p) : "memory");
  return r;
}
__device__ __forceinline__ f32x4 load_sc128f(const float* p) {
  f32x4 r;
  asm volatile("global_load_dwordx4 %0, %1, off sc0 sc1"
               : "=v"(r) : "v"(p) : "memory");
  return r;
}
__device__ __forceinline__ void store_sc128(unsigned short* p, u32x4 v) {
  asm volatile("global_store_dwordx4 %0, %1, off sc0 sc1" :: "v"(p), "v"(v) : "memory");
}
__device__ __forceinline__ void store_sc128f(float* p, f32x4 v) {
  asm volatile("global_store_dwordx4 %0, %1, off sc0 sc1" :: "v"(p), "v"(v) : "memory");
}
__device__ __forceinline__ void store_sc_i(int* p, int v) {
  asm volatile("global_store_dword %0, %1, off sc0 sc1" :: "v"(p), "v"(v) : "memory");
}
__device__ __forceinline__ int load_sc_i(const int* p) {
  int v;
  asm volatile("global_load_dword %0, %1, off sc0 sc1\n\ts_waitcnt vmcnt(0)"
               : "=v"(v) : "v"(p) : "memory");
  __builtin_amdgcn_sched_barrier(0);
  return v;
}
__device__ __forceinline__ void wait_vm0() {
  asm volatile("s_waitcnt vmcnt(0)" ::: "memory");
  __builtin_amdgcn_sched_barrier(0);
}

// Contention-free tree barrier. Monotonic step counters; no atomics.
__device__ __forceinline__ void grid_barrier(int* bar, int bid, int tid, int tau1) {
  wait_vm0();        // this wave's sc-stores confirmed (asm ops invisible to compiler)
  __syncthreads();   // => ALL waves' stores confirmed
  if (bid == 0) {
    if (tid >= 1 && tid < LSTM_NBLK) {
      int guard = 0;
      while (load_sc_i(&bar[tid * 32]) < tau1 && ++guard < (1 << 20))
        __builtin_amdgcn_s_sleep(1);
    }
    __syncthreads();                       // all arrivals observed
    if (tid < 8) store_sc_i(&bar[(GO_BASE + tid) * 32], tau1);
  } else {
    if (tid == 0) {
      store_sc_i(&bar[bid * 32], tau1);    // arrive (own line, no contention)
      int guard = 0;
      while (load_sc_i(&bar[(GO_BASE + (bid & 7)) * 32]) < tau1 && ++guard < (1 << 20))
        __builtin_amdgcn_s_sleep(1);
    }
    __syncthreads();
  }
}

// -------- merged L0 + L1-IH block (lag 0 for h0, partial1 for t'=tau-1) ----
__device__ __forceinline__ void run_l0_merged(const KParams& p, int g, int bid,
                                              unsigned short* ldsW, float* gates) {
  const unsigned short* __restrict__ strmA = p.strm[0] + (size_t)g * (4 * 13 * 512);
  const unsigned short* __restrict__ strmB = p.strm[1] + (size_t)g * (4 * 36 * 512);
  const float* __restrict__ bias           = p.bias[0];
  const unsigned short* __restrict__ xin   = p.xin0;
  unsigned short* __restrict__ own         = p.ring[0];

  const int tid  = threadIdx.x;
  const int lane = tid & 63;
  const int w    = tid >> 6;          // 16 waves
  const int m0   = (w >> 2) << 4;     // batch tile {0,16,32,48}
  const int kq   = w & 3;             // K-quarter
  const int r    = lane & 15;
  const int q    = lane >> 4;

  {  // stage Whh0 fragments into LDS; zero gate buffer
    const uint4* src = (const uint4*)(p.res[0] + (size_t)g * LDS_W_HALFS);
    uint4* dst = (uint4*)ldsW;
    for (int i = tid; i < LDS_W_HALFS / 8; i += 1024) dst[i] = src[i];
#pragma unroll
    for (int s2 = 0; s2 < 4; ++s2) gates[s2 * 1024 + tid] = 0.0f;
  }

  const int b_ = tid >> 4;            // elementwise: thread -> (batch, col)
  const int jp = tid & 15;
  const int jglob = g * 16 + jp;
  float bias4[4];
#pragma unroll
  for (int ss = 0; ss < 4; ++ss) bias4[ss] = bias[ss * 1152 + jglob];
  float c_val = 0.0f;
  __syncthreads();

  for (int tau = 0; tau < LSTM_WSTEPS; ++tau) {
    const bool doL0 = (tau < 512);        // gates0 -> h0_tau
    const bool doP  = (tau >= 1 && tau <= 512); // partial1 for t' = tau-1
    if (doL0 || doP) {
      // h0_{tau-1}: BOTH phases use this (same ring slot tau&7)
      const unsigned short* a2base =
          own + (size_t)(tau & 7) * (64 * 1152) + (size_t)(m0 + r) * 1152 + q * 8;
      u32x4 a2r[9];
#pragma unroll
      for (int i = 0; i < 9; ++i) a2r[i] = load_sc(a2base + (kq + 4 * i) * 32);
      wait_vm0();

      f32x4 acc[4]  = {{0,0,0,0},{0,0,0,0},{0,0,0,0},{0,0,0,0}};
      f32x4 pacc[4] = {{0,0,0,0},{0,0,0,0},{0,0,0,0},{0,0,0,0}};

      if (doL0) {
        // ---- gates0 phase 1: x0_tau @ Wih0^T (xin0 cached, strm0 cached) --
        const unsigned short* a1base =
            xin + (size_t)tau * (64 * 416) + (size_t)(m0 + r) * 416 + q * 8;
#pragma unroll
        for (int i = 0; i < 4; ++i) {
          int kb = kq + 4 * i;
          if (kb < 13) {
            f16x8 a = *(const f16x8*)(a1base + kb * 32);
#pragma unroll
            for (int s2 = 0; s2 < 4; ++s2) {
              f16x8 b = *(const f16x8*)&strmA[((size_t)(s2 * 13 + kb) * 64 + lane) * 8];
              acc[s2] = __builtin_amdgcn_mfma_f32_16x16x32_f16(a, b, acc[s2], 0, 0, 0);
            }
          }
        }
        // ---- gates0 phase 2: h0_{tau-1} @ Whh0^T (LDS-resident) ----------
#pragma unroll
        for (int i = 0; i < 9; ++i) {
          int kb = kq + 4 * i;
          f16x8 a = __builtin_bit_cast(f16x8, a2r[i]);
#pragma unroll
          for (int s2 = 0; s2 < 4; ++s2) {
            f16x8 b = *(const f16x8*)&ldsW[((s2 * 36 + kb) * 64 + lane) * 8];
            acc[s2] = __builtin_amdgcn_mfma_f32_16x16x32_f16(a, b, acc[s2], 0, 0, 0);
          }
        }
      }
      if (doP) {
        // ---- partial1: h0_{tau-1} @ Wih1^T-slice (strm1 cached, L2) ------
#pragma unroll
        for (int i = 0; i < 9; ++i) {
          int kb = kq + 4 * i;
          f16x8 a = __builtin_bit_cast(f16x8, a2r[i]);
#pragma unroll
          for (int s2 = 0; s2 < 4; ++s2) {
            f16x8 b = *(const f16x8*)&strmB[((size_t)(s2 * 36 + kb) * 64 + lane) * 8];
            pacc[s2] = __builtin_amdgcn_mfma_f32_16x16x32_f16(a, b, pacc[s2], 0, 0, 0);
          }
        }
      }

      // ---- reduce gates0; elementwise; h0 store ----
      if (doL0) {
#pragma unroll
        for (int s2 = 0; s2 < 4; ++s2)
#pragma unroll
          for (int i = 0; i < 4; ++i)   // C/D: col(n)=lane&15, row(m)=q*4+reg
            atomicAdd(&gates[s2 * 1024 + (m0 + q * 4 + i) * 16 + r], acc[s2][i]);
      }
      __syncthreads();
      if (doL0) {
        float pg[4];
#pragma unroll
        for (int s2 = 0; s2 < 4; ++s2) {
          pg[s2] = gates[s2 * 1024 + tid];
          gates[s2 * 1024 + tid] = 0.0f;
        }
        float ig = sigm_(pg[0] + bias4[0]);
        float fg = sigm_(pg[1] + bias4[1]);
        float gg = tanh_(pg[2] + bias4[2]);
        float og = sigm_(pg[3] + bias4[3]);
        c_val = fg * c_val + ig * gg;
        float h = og * tanh_(c_val);
        if (jglob >= 1150) h = 0.0f;

        unsigned v0  = (unsigned)f2h(h);
        unsigned o1  = __shfl_down(v0, 1);
        unsigned p01 = v0 | (o1 << 16);
        unsigned o2  = __shfl_down(p01, 2);
        unsigned o4a = __shfl_down(p01, 4);
        unsigned o4b = __shfl_down(o2, 4);
        if ((lane & 7) == 0) {
          u32x4 pk; pk[0] = p01; pk[1] = o2; pk[2] = o4a; pk[3] = o4b;
          store_sc128(own + (size_t)(((tau + 1) & 7) * 64 + b_) * 1152 + jglob, pk);
        }
      }
      // ---- reduce partial1 (after gate slots re-zeroed by all threads) ----
      __syncthreads();
      if (doP) {
#pragma unroll
        for (int s2 = 0; s2 < 4; ++s2)
#pragma unroll
          for (int i = 0; i < 4; ++i)
            atomicAdd(&gates[s2 * 1024 + (m0 + q * 4 + i) * 16 + r], pacc[s2][i]);
      }
      __syncthreads();
      if (doP) {
        f32x4 pk;
#pragma unroll
        for (int s2 = 0; s2 < 4; ++s2) {
          pk[s2] = gates[s2 * 1024 + tid];
          gates[s2 * 1024 + tid] = 0.0f;
        }
        // partial[(tau-1)&1][g][tid][0..3]; HH reads it next step
        store_sc128f(p.part + ((size_t)(((tau - 1) & 1) * 72 + g) * 1024 + tid) * 4, pk);
      }
    }
    grid_barrier(p.bar, bid, tid, tau + 1);
  }
}

// ---------------- L1 recurrent half: gates/elementwise/h (lag 2) -----------
__device__ __forceinline__ void run_l1_hh(const KParams& p, int g, int bid,
                                          unsigned short* ldsW, float* gates) {
  unsigned short* __restrict__ own = p.ring[1];
  const int tid  = threadIdx.x;
  const int lane = tid & 63;
  const int w    = tid >> 6;
  const int m0   = (w >> 2) << 4;
  const int kq   = w & 3;
  const int r    = lane & 15;
  const int q    = lane >> 4;

  {  // stage Whh1 fragments
    const uint4* src = (const uint4*)(p.res[1] + (size_t)g * LDS_W_HALFS);
    uint4* dst = (uint4*)ldsW;
    for (int i = tid; i < LDS_W_HALFS / 8; i += 1024) dst[i] = src[i];
#pragma unroll
    for (int s2 = 0; s2 < 4; ++s2) gates[s2 * 1024 + tid] = 0.0f;
  }

  const int b_ = tid >> 4;
  const int jp = tid & 15;
  const int jglob = g * 16 + jp;
  float bias4[4];
#pragma unroll
  for (int ss = 0; ss < 4; ++ss) bias4[ss] = p.bias[1][ss * 1152 + jglob];
  float c_val = 0.0f;
  __syncthreads();

  for (int tau = 0; tau < LSTM_WSTEPS; ++tau) {
    const int t = tau - 2;
    if (t >= 0 && t < 512) {
      f32x4 acc[4] = {{0,0,0,0},{0,0,0,0},{0,0,0,0},{0,0,0,0}};
      const unsigned short* a2base =
          own + (size_t)(t & 7) * (64 * 1152) + (size_t)(m0 + r) * 1152 + q * 8;
      u32x4 a2r[9];
#pragma unroll
      for (int i = 0; i < 9; ++i) a2r[i] = load_sc(a2base + (kq + 4 * i) * 32);
      // IH partial (written last tau by merged block; ordered by the barrier)
      f32x4 pl = load_sc128f(p.part + ((size_t)((t & 1) * 72 + g) * 1024 + tid) * 4);
      wait_vm0();
#pragma unroll
      for (int i = 0; i < 9; ++i) {
        int kb = kq + 4 * i;
        f16x8 a = __builtin_bit_cast(f16x8, a2r[i]);
#pragma unroll
        for (int s2 = 0; s2 < 4; ++s2) {
          f16x8 b = *(const f16x8*)&ldsW[((s2 * 36 + kb) * 64 + lane) * 8];
          acc[s2] = __builtin_amdgcn_mfma_f32_16x16x32_f16(a, b, acc[s2], 0, 0, 0);
        }
      }
#pragma unroll
      for (int s2 = 0; s2 < 4; ++s2)
#pragma unroll
        for (int i = 0; i < 4; ++i)
          atomicAdd(&gates[s2 * 1024 + (m0 + q * 4 + i) * 16 + r], acc[s2][i]);
      __syncthreads();

      float pg[4];
#pragma unroll
      for (int s2 = 0; s2 < 4; ++s2) {
        pg[s2] = gates[s2 * 1024 + tid];
        gates[s2 * 1024 + tid] = 0.0f;
      }
      float ig = sigm_(pg[0] + pl[0] + bias4[0]);
      float fg = sigm_(pg[1] + pl[1] + bias4[1]);
      float gg = tanh_(pg[2] + pl[2] + bias4[2]);
      float og = sigm_(pg[3] + pl[3] + bias4[3]);
      c_val = fg * c_val + ig * gg;
      float h = og * tanh_(c_val);
      if (jglob >= 1150) h = 0.0f;

      unsigned v0  = (unsigned)f2h(h);
      unsigned o1  = __shfl_down(v0, 1);
      unsigned p01 = v0 | (o1 << 16);
      unsigned o2  = __shfl_down(p01, 2);
      unsigned o4a = __shfl_down(p01, 4);
      unsigned o4b = __shfl_down(o2, 4);
      if ((lane & 7) == 0) {
        u32x4 pk2; pk2[0] = p01; pk2[1] = o2; pk2[2] = o4a; pk2[3] = o4b;
        store_sc128(own + (size_t)(((t + 1) & 7) * 64 + b_) * 1152 + jglob, pk2);
      }
    }
    grid_barrier(p.bar, bid, tid, tau + 1);
  }
}

// ---------------- L2 layer (lag 3): Wih2 resident, Whh2 streamed -----------
__device__ __forceinline__ void run_l2(const KParams& p, int g, int bid,
                                       unsigned short* ldsW, float* gates) {
  const unsigned short* __restrict__ strm = p.strm[2] + (size_t)g * (4 * 13 * 512);
  const unsigned short* __restrict__ xin  = p.ring[1];
  unsigned short* __restrict__ own        = p.ring[2];

  const int tid  = threadIdx.x;
  const int lane = tid & 63;
  const int w    = tid >> 6;
  const int m0   = (w >> 2) << 4;
  const int kq   = w & 3;
  const int r    = lane & 15;
  const int q    = lane >> 4;

  {  // stage Wih2 fragments
    const uint4* src = (const uint4*)(p.res[2] + (size_t)g * LDS_W_HALFS);
    uint4* dst = (uint4*)ldsW;
    for (int i = tid; i < LDS_W_HALFS / 8; i += 1024) dst[i] = src[i];
#pragma unroll
    for (int s2 = 0; s2 < 4; ++s2) gates[s2 * 1024 + tid] = 0.0f;
  }

  const int b_ = tid >> 4;
  const int jp = tid & 15;
  const int jglob = g * 16 + jp;
  float bias4[4];
#pragma unroll
  for (int ss = 0; ss < 4; ++ss) bias4[ss] = p.bias[2][ss * 1152 + jglob];
  float c_val = 0.0f;
  __syncthreads();

  for (int tau = 0; tau < LSTM_WSTEPS; ++tau) {
    const int t = tau - 3;
    if (t >= 0 && t < 512) {
      f32x4 acc[4] = {{0,0,0,0},{0,0,0,0},{0,0,0,0},{0,0,0,0}};
      const unsigned short* a1base =
          xin + (size_t)((t + 1) & 7) * (64 * 1152) + (size_t)(m0 + r) * 1152 + q * 8;
      const unsigned short* a2base =
          own + (size_t)(t & 7) * (64 * 416) + (size_t)(m0 + r) * 416 + q * 8;

      u32x4 a1r[9]; u32x4 a2r[4];
#pragma unroll
      for (int i = 0; i < 9; ++i) a1r[i] = load_sc(a1base + (kq + 4 * i) * 32);
#pragma unroll
      for (int i = 0; i < 4; ++i) {
        int kb = kq + 4 * i;
        if (kb < 13) a2r[i] = load_sc(a2base + kb * 32);
      }
      wait_vm0();

      // phase 1: h1_t @ Wih2^T (LDS-resident)
#pragma unroll
      for (int i = 0; i < 9; ++i) {
        int kb = kq + 4 * i;
        f16x8 a = __builtin_bit_cast(f16x8, a1r[i]);
#pragma unroll
        for (int s2 = 0; s2 < 4; ++s2) {
          f16x8 b = *(const f16x8*)&ldsW[((s2 * 36 + kb) * 64 + lane) * 8];
          acc[s2] = __builtin_amdgcn_mfma_f32_16x16x32_f16(a, b, acc[s2], 0, 0, 0);
        }
      }
      // phase 2: h2_{t-1} @ Whh2^T (streamed, L2-cached)
#pragma unroll
      for (int i = 0; i < 4; ++i) {
        int kb = kq + 4 * i;
        if (kb < 13) {
          f16x8 a = __builtin_bit_cast(f16x8, a2r[i]);
#pragma unroll
          for (int s2 = 0; s2 < 4; ++s2) {
            f16x8 b = *(const f16x8*)&strm[((size_t)(s2 * 13 + kb) * 64 + lane) * 8];
            acc[s2] = __builtin_amdgcn_mfma_f32_16x16x32_f16(a, b, acc[s2], 0, 0, 0);
          }
        }
      }

#pragma unroll
      for (int s2 = 0; s2 < 4; ++s2)
#pragma unroll
        for (int i = 0; i < 4; ++i)
          atomicAdd(&gates[s2 * 1024 + (m0 + q * 4 + i) * 16 + r], acc[s2][i]);
      __syncthreads();

      float pg[4];
#pragma unroll
      for (int s2 = 0; s2 < 4; ++s2) {
        pg[s2] = gates[s2 * 1024 + tid];
        gates[s2 * 1024 + tid] = 0.0f;
      }
      float ig = sigm_(pg[0] + bias4[0]);
      float fg = sigm_(pg[1] + bias4[1]);
      float gg = tanh_(pg[2] + bias4[2]);
      float og = sigm_(pg[3] + bias4[3]);
      c_val = fg * c_val + ig * gg;
      float h = og * tanh_(c_val);
      if (jglob >= 400) h = 0.0f;

      unsigned v0  = (unsigned)f2h(h);
      unsigned o1  = __shfl_down(v0, 1);
      unsigned p01 = v0 | (o1 << 16);
      unsigned o2  = __shfl_down(p01, 2);
      unsigned o4a = __shfl_down(p01, 4);
      unsigned o4b = __shfl_down(o2, 4);
      if ((lane & 7) == 0) {
        u32x4 pk; pk[0] = p01; pk[1] = o2; pk[2] = o4a; pk[3] = o4b;
        store_sc128(own + (size_t)(((t + 1) & 7) * 64 + b_) * 416 + jglob, pk);
      }
      if (jglob < 400)
        p.out[((size_t)t * 64 + b_) * 400 + jglob] = h;
    }
    grid_barrier(p.bar, bid, tid, tau + 1);
  }
}

__global__ void __launch_bounds__(1024) lstm_persistent(KParams p) {
  extern __shared__ unsigned short smem[];
  unsigned short* ldsW = smem;
  float* gates = (float*)(smem + LDS_W_HALFS);
  const int bid = blockIdx.x;
  if (bid < 72)       run_l0_merged(p, bid, bid, ldsW, gates);
  else if (bid < 144) run_l1_hh(p, bid - 72, bid, ldsW, gates);
  else                run_l2(p, bid - 144, bid, ldsW, gates);
}

// --- prep: fp32 [4*Jext][K] -> fp16 fragment-major [g][(s*NKB+kb)*64+lane][8] ---
__global__ void prep_weights(const float* __restrict__ src,
                             unsigned short* __restrict__ dst,
                             int Jext, int jg, int K, int NKB) {
  const int n = jg * 4 * NKB * 512;
  for (int idx = blockIdx.x * blockDim.x + threadIdx.x; idx < n;
       idx += gridDim.x * blockDim.x) {
    int e = idx & 7;
    int t2 = idx >> 3;
    int ln = t2 & 63; t2 >>= 6;
    int kb = t2 % NKB; t2 /= NKB;
    int s = t2 & 3;
    int g = t2 >> 2;
    int j = g * 16 + (ln & 15);
    int k = kb * 32 + (ln >> 4) * 8 + e;
    unsigned short v = 0;
    if (j < Jext && k < K) v = f2h(src[(size_t)(s * Jext + j) * K + k]);
    dst[idx] = v;
  }
}

__global__ void prep_bias(const float* __restrict__ bih,
                          const float* __restrict__ bhh,
                          float* __restrict__ dst, int Dh) {
  const int n = 4 * 1152;
  for (int idx = blockIdx.x * blockDim.x + threadIdx.x; idx < n;
       idx += gridDim.x * blockDim.x) {
    int s = idx / 1152, j = idx % 1152;
    float v = 0.0f;
    if (j < Dh) v = bih[s * Dh + j] + bhh[s * Dh + j];
    dst[idx] = v;
  }
}

// gather emb[tokens] (fp32) into padded fp16 [512*64][416] (cols 400..415 = 0)
__global__ void prep_gather(const int* __restrict__ tokens,
                            const float* __restrict__ emb,
                            unsigned short* __restrict__ xin0) {
  const int n = 512 * 64 * 52;
  for (int idx = blockIdx.x * blockDim.x + threadIdx.x; idx < n;
       idx += gridDim.x * blockDim.x) {
    int row = idx / 52;
    int cp  = idx - row * 52;
    unsigned short v[8] = {0, 0, 0, 0, 0, 0, 0, 0};
    if (cp < 50) {
      const float* src = emb + (size_t)tokens[row] * 400 + cp * 8;
      float4 a = *(const float4*)(src);
      float4 b = *(const float4*)(src + 4);
      v[0] = f2h(a.x); v[1] = f2h(a.y); v[2] = f2h(a.z); v[3] = f2h(a.w);
      v[4] = f2h(b.x); v[5] = f2h(b.y); v[6] = f2h(b.z); v[7] = f2h(b.w);
    }
    *(uint4*)(xin0 + (size_t)row * 416 + cp * 8) = *(const uint4*)v;
  }
}

extern "C" void kernel_launch(void* const* d_in, const int* in_sizes, int n_in,
                              void* d_out, int out_size, void* d_ws, size_t ws_size,
                              hipStream_t stream) {
  const int*   tokens = (const int*)d_in[0];
  const float* emb  = (const float*)d_in[1];
  const float* Wih0 = (const float*)d_in[2];
  const float* Whh0 = (const float*)d_in[3];
  const float* bih0 = (const float*)d_in[4];
  const float* bhh0 = (const float*)d_in[5];
  const float* Wih1 = (const float*)d_in[8];
  const float* Whh1 = (const float*)d_in[9];
  const float* bih1 = (const float*)d_in[10];
  const float* bhh1 = (const float*)d_in[11];
  const float* Wih2 = (const float*)d_in[14];
  const float* Whh2 = (const float*)d_in[15];
  const float* bih2 = (const float*)d_in[16];
  const float* bhh2 = (const float*)d_in[17];

  char* ws = (char*)d_ws;
  size_t off = 0;
  auto alloc = [&](size_t bytes) -> char* {
    char* ptr = ws + off;
    off += (bytes + 255) & ~(size_t)255;
    return ptr;
  };
  unsigned short* res0  = (unsigned short*)alloc(72ull * 4 * 36 * 512 * 2);
  unsigned short* res1  = (unsigned short*)alloc(72ull * 4 * 36 * 512 * 2);
  unsigned short* res2  = (unsigned short*)alloc(25ull * 4 * 36 * 512 * 2);
  unsigned short* strm0 = (unsigned short*)alloc(72ull * 4 * 13 * 512 * 2);
  unsigned short* strm1 = (unsigned short*)alloc(72ull * 4 * 36 * 512 * 2);
  unsigned short* strm2 = (unsigned short*)alloc(25ull * 4 * 13 * 512 * 2);
  float* bias0 = (float*)alloc(4ull * 1152 * 4);
  float* bias1 = (float*)alloc(4ull * 1152 * 4);
  float* bias2 = (float*)alloc(4ull * 1152 * 4);
  unsigned short* xin0  = (unsigned short*)alloc(512ull * 64 * 416 * 2);
  unsigned short* ring0 = (unsigned short*)alloc(8ull * 64 * 1152 * 2);
  unsigned short* ring1 = (unsigned short*)alloc(8ull * 64 * 1152 * 2);
  unsigned short* ring2 = (unsigned short*)alloc(8ull * 64 * 416 * 2);
  float* part = (float*)alloc(2ull * 72 * 1024 * 4 * 4);        // 2.36 MB
  int* bar = (int*)alloc((GO_BASE + 8) * 32 * 4);   // arrive[169]+go[8], 128B lines
  if (off > ws_size) return;

  hipLaunchKernelGGL(prep_gather, dim3(2048), dim3(256), 0, stream, tokens, emb, xin0);
  hipLaunchKernelGGL(prep_weights, dim3(4096), dim3(256), 0, stream, Whh0, res0, 1150, 72, 1150, 36);
  hipLaunchKernelGGL(prep_weights, dim3(4096), dim3(256), 0, stream, Whh1, res1, 1150, 72, 1150, 36);
  hipLaunchKernelGGL(prep_weights, dim3(4096), dim3(256), 0, stream, Wih2, res2, 400, 25, 1150, 36);
  hipLaunchKernelGGL(prep_weights, dim3(4096), dim3(256), 0, stream, Wih0, strm0, 1150, 72, 400, 13);
  hipLaunchKernelGGL(prep_weights, dim3(4096), dim3(256), 0, stream, Wih1, strm1, 1150, 72, 1150, 36);
  hipLaunchKernelGGL(prep_weights, dim3(4096), dim3(256), 0, stream, Whh2, strm2, 400, 25, 400, 13);
  hipLaunchKernelGGL(prep_bias, dim3(8), dim3(256), 0, stream, bih0, bhh0, bias0, 1150);
  hipLaunchKernelGGL(prep_bias, dim3(8), dim3(256), 0, stream, bih1, bhh1, bias1, 1150);
  hipLaunchKernelGGL(prep_bias, dim3(8), dim3(256), 0, stream, bih2, bhh2, bias2, 400);
  (void)hipMemsetAsync(ring0, 0, 8ull * 64 * 1152 * 2, stream);
  (void)hipMemsetAsync(ring1, 0, 8ull * 64 * 1152 * 2, stream);
  (void)hipMemsetAsync(ring2, 0, 8ull * 64 * 416 * 2, stream);
  (void)hipMemsetAsync(bar, 0, (GO_BASE + 8) * 32 * 4, stream);

  KParams kp;
  kp.res[0] = res0;  kp.res[1] = res1;  kp.res[2] = res2;
  kp.strm[0] = strm0; kp.strm[1] = strm1; kp.strm[2] = strm2;
  kp.bias[0] = bias0; kp.bias[1] = bias1; kp.bias[2] = bias2;
  kp.xin0 = xin0;
  kp.ring[0] = ring0; kp.ring[1] = ring1; kp.ring[2] = ring2;
  kp.part = part;
  kp.out = (float*)d_out;
  kp.bar = bar;

  (void)hipFuncSetAttribute((const void*)lstm_persistent,
                            hipFuncAttributeMaxDynamicSharedMemorySize,
                            LDS_TOTAL_BYTES);
  hipLaunchKernelGGL(lstm_persistent, dim3(LSTM_NBLK), dim3(1024),
                     LDS_TOTAL_BYTES, stream, kp);
}

// Round 4
// 15258.511 us; speedup vs baseline: 2.4162x; 2.4162x over previous
//
#include <hip/hip_runtime.h>
#include <hip/hip_bf16.h>
#include <cstdint>
#include <cstddef>

// ---------------------------------------------------------------------------
// 3-layer LSTM (AWD-LSTM encoder, eval), S=512 B=64 V=50000 E=400 H=1150.
// FP32 in/out; fp16 MFMA compute with fp32 accumulation.
//
// r9: full-sequence h buffers + plain cached consumer reads. r8 REVERTED
// (streaming Wih1 from L2 thrashed: FETCH 21 MB/step of HBM refetch = the
// whole step time). r6 structure restored (all four big matrices
// LDS-resident). r6's residual was ~36 MB/step of sc0sc1 bypass ring reads
// at a measured ~1.0-1.2 TB/s device-coherent-read ceiling. Fix: h rings
// -> full-seq buffers hseq[t][64][D] (h_t at slot t+1, slot 0 zeroed;
// +179 MB ws). Producers write through (sc0sc1, MALL-confirmed before the
// barrier arrive). Consumers use PLAIN CACHED loads: every read address is
// VIRGIN (written exactly once, read only after), so no L1/L2 can hold a
// stale copy, and the fill comes through the memory-side Infinity Cache
// which holds the written data. No fence needed; correct under any
// block->XCD mapping. Per-XCD L2 now deduplicates the 144/97-consumer
// reads (first-touch ~2.6 MB/step). Only the L1-partial handoff (1.2
// MB/step, parity-2 address reuse) stays on the sc bypass path.
// From r6: L1 split (IH: Wih1 LDS-resident, lag 1 -> partial; HH: Whh1
// LDS-resident, lag 2), 241 blocks (72/72/72/25) co-resident, tree
// barrier, fragment-major LDS weights, K-split waves, shuffle-packed 16B
// h stores, sched_barrier(0) after asm waitcnts (rule #18).
// ---------------------------------------------------------------------------

typedef _Float16 f16x8 __attribute__((ext_vector_type(8)));
typedef float f32x4 __attribute__((ext_vector_type(4)));
typedef unsigned int u32x4 __attribute__((ext_vector_type(4)));

#define LSTM_NBLK   241
#define LSTM_WSTEPS 515
#define LDS_W_HALFS (4 * 36 * 64 * 8)             // 73728 halves = 147456 B
#define LDS_TOTAL_BYTES (LDS_W_HALFS * 2 + 16384) // + 4x1024 fp32 gates = 163840
#define GO_BASE 248                               // go lines start at this slot

struct KParams {
  const unsigned short* res[3];   // resident W: Whh0, Whh1, Wih2 (frag-major, NKB=36)
  const unsigned short* strm[3];  // Wih0(13), Wih1(36), Whh2(13) frag-major
  const float* bias[3];           // bih+bhh fused [4][1152] fp32
  const unsigned short* xin0;     // gathered emb  [512][64][416] fp16 (immutable)
  unsigned short* hseq[3];        // full-seq h: [513][64][HSTR] fp16 (h_t at slot t+1)
  float* part;                    // L1 partial gates [2][72][1024][4] fp32
  float* out;                     // [512][64][400] fp32
  int* bar;                       // arrive[241] + go[8] flags, 128B-spaced
};

__device__ __forceinline__ float sigm_(float x) { return 1.0f / (1.0f + __expf(-x)); }
__device__ __forceinline__ float tanh_(float x) { return 2.0f * sigm_(2.0f * x) - 1.0f; }
__device__ __forceinline__ unsigned short f2h(float x) {
  _Float16 h = (_Float16)x;
  return __builtin_bit_cast(unsigned short, h);
}
// Device-coherent ops: bypass L1/L2, hit the coherence point (MALL).
__device__ __forceinline__ f32x4 load_sc128f(const float* p) {
  f32x4 r;
  asm volatile("global_load_dwordx4 %0, %1, off sc0 sc1"
               : "=v"(r) : "v"(p) : "memory");
  return r;
}
__device__ __forceinline__ void store_sc128(unsigned short* p, u32x4 v) {
  asm volatile("global_store_dwordx4 %0, %1, off sc0 sc1" :: "v"(p), "v"(v) : "memory");
}
__device__ __forceinline__ void store_sc128f(float* p, f32x4 v) {
  asm volatile("global_store_dwordx4 %0, %1, off sc0 sc1" :: "v"(p), "v"(v) : "memory");
}
__device__ __forceinline__ void store_sc_i(int* p, int v) {
  asm volatile("global_store_dword %0, %1, off sc0 sc1" :: "v"(p), "v"(v) : "memory");
}
__device__ __forceinline__ int load_sc_i(const int* p) {
  int v;
  asm volatile("global_load_dword %0, %1, off sc0 sc1\n\ts_waitcnt vmcnt(0)"
               : "=v"(v) : "v"(p) : "memory");
  __builtin_amdgcn_sched_barrier(0);
  return v;
}
__device__ __forceinline__ void wait_vm0() {
  asm volatile("s_waitcnt vmcnt(0)" ::: "memory");
  __builtin_amdgcn_sched_barrier(0);
}

// Contention-free tree barrier. Monotonic step counters; no atomics.
__device__ __forceinline__ void grid_barrier(int* bar, int bid, int tid, int tau1) {
  wait_vm0();        // this wave's sc-stores confirmed (asm ops invisible to compiler)
  __syncthreads();   // => ALL waves' stores confirmed
  if (bid == 0) {
    if (tid >= 1 && tid < LSTM_NBLK) {
      int guard = 0;
      while (load_sc_i(&bar[tid * 32]) < tau1 && ++guard < (1 << 20))
        __builtin_amdgcn_s_sleep(1);
    }
    __syncthreads();                       // all arrivals observed
    if (tid < 8) store_sc_i(&bar[(GO_BASE + tid) * 32], tau1);
  } else {
    if (tid == 0) {
      store_sc_i(&bar[bid * 32], tau1);    // arrive (own line, no contention)
      int guard = 0;
      while (load_sc_i(&bar[(GO_BASE + (bid & 7)) * 32]) < tau1 && ++guard < (1 << 20))
        __builtin_amdgcn_s_sleep(1);
    }
    __syncthreads();
  }
}

// ---------------- edge layers (L0 lag 0, L2 lag 3) -------------------------
template<int L, int LAG>
__device__ __forceinline__ void run_layer(const KParams& p, int g, int bid,
                                          unsigned short* ldsW, float* gates) {
  constexpr int DH    = (L == 2) ? 400 : 1150;
  constexpr int NKB1  = (L == 0) ? 13 : 36;    // input-phase K chunks (of 32)
  constexpr int NKB2  = (L == 2) ? 13 : 36;    // recurrent-phase K chunks
  constexpr int XSTR  = (L == 0) ? 416 : 1152; // input-A row stride
  constexpr int HSTR  = (L == 2) ? 416 : 1152; // own-seq row stride
  constexpr bool B1_RES = (L == 2);            // L2: Wih resident, Whh streamed
  constexpr int NKB_ST = B1_RES ? NKB2 : NKB1; // streamed-W chunk count

  const unsigned short* __restrict__ strm = p.strm[L] + (size_t)g * (4 * NKB_ST * 512);
  const float* __restrict__ bias          = p.bias[L];
  const unsigned short* __restrict__ xin  = (L == 0) ? p.xin0 : p.hseq[L - 1];
  unsigned short* __restrict__ own        = p.hseq[L];

  const int tid  = threadIdx.x;
  const int lane = tid & 63;
  const int w    = tid >> 6;          // 16 waves
  const int m0   = (w >> 2) << 4;     // batch tile {0,16,32,48}
  const int kq   = w & 3;             // K-quarter
  const int r    = lane & 15;
  const int q    = lane >> 4;

  // Stage resident W (fragment-major, contiguous) into LDS; zero gate buffer.
  {
    const uint4* src = (const uint4*)(p.res[L] + (size_t)g * LDS_W_HALFS);
    uint4* dst = (uint4*)ldsW;
    for (int i = tid; i < LDS_W_HALFS / 8; i += 1024) dst[i] = src[i];
#pragma unroll
    for (int s2 = 0; s2 < 4; ++s2) gates[s2 * 1024 + tid] = 0.0f;
  }

  const int b_ = tid >> 4;            // elementwise: thread -> (batch, col)
  const int jp = tid & 15;
  const int jglob = g * 16 + jp;
  float bias4[4];
#pragma unroll
  for (int ss = 0; ss < 4; ++ss) bias4[ss] = bias[ss * 1152 + jglob];
  float c_val = 0.0f;
  __syncthreads();

  for (int tau = 0; tau < LSTM_WSTEPS; ++tau) {
    const int t = tau - LAG;
    if (t >= 0 && t < 512) {
      f32x4 acc[4] = {{0,0,0,0},{0,0,0,0},{0,0,0,0},{0,0,0,0}};

      // xin slot: L0 -> emb[t]; L2 -> h1_t at slot (t+1). own slot t = h_{t-1}.
      const size_t slot1 = (L == 0) ? (size_t)t : (size_t)(t + 1);
      const unsigned short* a1base = xin + slot1 * (64 * XSTR) + (size_t)(m0 + r) * XSTR + q * 8;
      const unsigned short* a2base = own + (size_t)t * (64 * HSTR) + (size_t)(m0 + r) * HSTR + q * 8;

      // ---- preload A fragments (plain cached loads; virgin addrs => fresh) ----
      f16x8 a1r[9]; f16x8 a2r[9];
      if constexpr (L != 0) {
#pragma unroll
        for (int i = 0; i < 9; ++i) {
          int kb = kq + 4 * i;
          if (NKB1 == 36 || kb < NKB1) a1r[i] = *(const f16x8*)(a1base + kb * 32);
        }
      }
#pragma unroll
      for (int i = 0; i < 9; ++i) {
        int kb = kq + 4 * i;
        if (i < ((NKB2 == 36) ? 9 : 4) && (NKB2 == 36 || kb < NKB2))
          a2r[i] = *(const f16x8*)(a2base + kb * 32);
      }

      // ---- phase 1: x_t @ Wih^T ----
#pragma unroll
      for (int i = 0; i < ((NKB1 == 36) ? 9 : 4); ++i) {
        int kb = kq + 4 * i;
        if (NKB1 == 36 || kb < NKB1) {
          f16x8 a = (L == 0) ? *(const f16x8*)(a1base + kb * 32) : a1r[i];
#pragma unroll
          for (int s2 = 0; s2 < 4; ++s2) {
            f16x8 b = B1_RES
              ? *(const f16x8*)&ldsW[((s2 * 36 + kb) * 64 + lane) * 8]
              : *(const f16x8*)&strm[((size_t)(s2 * NKB_ST + kb) * 64 + lane) * 8];
            acc[s2] = __builtin_amdgcn_mfma_f32_16x16x32_f16(a, b, acc[s2], 0, 0, 0);
          }
        }
      }
      // ---- phase 2: h_{t-1} @ Whh^T ----
#pragma unroll
      for (int i = 0; i < ((NKB2 == 36) ? 9 : 4); ++i) {
        int kb = kq + 4 * i;
        if (NKB2 == 36 || kb < NKB2) {
          f16x8 a = a2r[i];
#pragma unroll
          for (int s2 = 0; s2 < 4; ++s2) {
            f16x8 b = B1_RES
              ? *(const f16x8*)&strm[((size_t)(s2 * NKB_ST + kb) * 64 + lane) * 8]
              : *(const f16x8*)&ldsW[((s2 * 36 + kb) * 64 + lane) * 8];
            acc[s2] = __builtin_amdgcn_mfma_f32_16x16x32_f16(a, b, acc[s2], 0, 0, 0);
          }
        }
      }

      // ---- reduce partial gates across the 4 kq-waves via LDS atomics ----
#pragma unroll
      for (int s2 = 0; s2 < 4; ++s2)
#pragma unroll
        for (int i = 0; i < 4; ++i)   // C/D: col(n)=lane&15, row(m)=q*4+reg
          atomicAdd(&gates[s2 * 1024 + (m0 + q * 4 + i) * 16 + r], acc[s2][i]);
      __syncthreads();

      // ---- LSTM elementwise (fp32); re-zero gate slots after reading ----
      float pg[4];
#pragma unroll
      for (int s2 = 0; s2 < 4; ++s2) {
        pg[s2] = gates[s2 * 1024 + tid];
        gates[s2 * 1024 + tid] = 0.0f;
      }
      float ig = sigm_(pg[0] + bias4[0]);
      float fg = sigm_(pg[1] + bias4[1]);
      float gg = tanh_(pg[2] + bias4[2]);
      float og = sigm_(pg[3] + bias4[3]);
      c_val = fg * c_val + ig * gg;
      float h = og * tanh_(c_val);
      if (jglob >= DH) h = 0.0f;       // pad cols inside the 16B strip stay 0

      // ---- wave-shuffle pack 16 halves -> 16B sc-stores (8x fewer writes) ----
      unsigned v0  = (unsigned)f2h(h);
      unsigned o1  = __shfl_down(v0, 1);
      unsigned p01 = v0 | (o1 << 16);
      unsigned o2  = __shfl_down(p01, 2);
      unsigned o4a = __shfl_down(p01, 4);
      unsigned o4b = __shfl_down(o2, 4);
      if ((lane & 7) == 0) {           // jp in {0,8}: owns halves jglob..jglob+7
        u32x4 pk; pk[0] = p01; pk[1] = o2; pk[2] = o4a; pk[3] = o4b;
        store_sc128(own + ((size_t)(t + 1) * 64 + b_) * HSTR + jglob, pk);
      }
      if (L == 2 && jglob < DH)
        p.out[((size_t)t * 64 + b_) * 400 + jglob] = h;
    }
    grid_barrier(p.bar, bid, tid, tau + 1);
  }
}

// ---------------- L1 input half: partial = x_t @ Wih1^T (lag 1) ------------
__device__ __forceinline__ void run_l1_ih(const KParams& p, int g, int bid,
                                          unsigned short* ldsW, float* gates) {
  const unsigned short* __restrict__ xin = p.hseq[0];
  const int tid  = threadIdx.x;
  const int lane = tid & 63;
  const int w    = tid >> 6;
  const int m0   = (w >> 2) << 4;
  const int kq   = w & 3;
  const int r    = lane & 15;
  const int q    = lane >> 4;

  {  // stage Wih1 fragments (strm1 layout == res layout, NKB=36)
    const uint4* src = (const uint4*)(p.strm[1] + (size_t)g * LDS_W_HALFS);
    uint4* dst = (uint4*)ldsW;
    for (int i = tid; i < LDS_W_HALFS / 8; i += 1024) dst[i] = src[i];
#pragma unroll
    for (int s2 = 0; s2 < 4; ++s2) gates[s2 * 1024 + tid] = 0.0f;
  }
  __syncthreads();

  for (int tau = 0; tau < LSTM_WSTEPS; ++tau) {
    const int t = tau - 1;
    if (t >= 0 && t < 512) {
      f32x4 acc[4] = {{0,0,0,0},{0,0,0,0},{0,0,0,0},{0,0,0,0}};
      // x1_t = h0_t, stored at hseq0 slot t+1 (written by L0 at step tau-1)
      const unsigned short* a1base =
          xin + (size_t)(t + 1) * (64 * 1152) + (size_t)(m0 + r) * 1152 + q * 8;
      f16x8 a1r[9];
#pragma unroll
      for (int i = 0; i < 9; ++i) a1r[i] = *(const f16x8*)(a1base + (kq + 4 * i) * 32);
#pragma unroll
      for (int i = 0; i < 9; ++i) {
        int kb = kq + 4 * i;
        f16x8 a = a1r[i];
#pragma unroll
        for (int s2 = 0; s2 < 4; ++s2) {
          f16x8 b = *(const f16x8*)&ldsW[((s2 * 36 + kb) * 64 + lane) * 8];
          acc[s2] = __builtin_amdgcn_mfma_f32_16x16x32_f16(a, b, acc[s2], 0, 0, 0);
        }
      }
#pragma unroll
      for (int s2 = 0; s2 < 4; ++s2)
#pragma unroll
        for (int i = 0; i < 4; ++i)
          atomicAdd(&gates[s2 * 1024 + (m0 + q * 4 + i) * 16 + r], acc[s2][i]);
      __syncthreads();
      f32x4 pk;
#pragma unroll
      for (int s2 = 0; s2 < 4; ++s2) {
        pk[s2] = gates[s2 * 1024 + tid];
        gates[s2 * 1024 + tid] = 0.0f;
      }
      // partial[t&1][g][tid][0..3], one coalesced dwordx4 write-through/thread
      store_sc128f(p.part + ((size_t)((t & 1) * 72 + g) * 1024 + tid) * 4, pk);
    }
    grid_barrier(p.bar, bid, tid, tau + 1);
  }
}

// ---------------- L1 recurrent half: gates/elementwise/h (lag 2) -----------
__device__ __forceinline__ void run_l1_hh(const KParams& p, int g, int bid,
                                          unsigned short* ldsW, float* gates) {
  unsigned short* __restrict__ own = p.hseq[1];
  const int tid  = threadIdx.x;
  const int lane = tid & 63;
  const int w    = tid >> 6;
  const int m0   = (w >> 2) << 4;
  const int kq   = w & 3;
  const int r    = lane & 15;
  const int q    = lane >> 4;

  {  // stage Whh1 fragments
    const uint4* src = (const uint4*)(p.res[1] + (size_t)g * LDS_W_HALFS);
    uint4* dst = (uint4*)ldsW;
    for (int i = tid; i < LDS_W_HALFS / 8; i += 1024) dst[i] = src[i];
#pragma unroll
    for (int s2 = 0; s2 < 4; ++s2) gates[s2 * 1024 + tid] = 0.0f;
  }

  const int b_ = tid >> 4;
  const int jp = tid & 15;
  const int jglob = g * 16 + jp;
  float bias4[4];
#pragma unroll
  for (int ss = 0; ss < 4; ++ss) bias4[ss] = p.bias[1][ss * 1152 + jglob];
  float c_val = 0.0f;
  __syncthreads();

  for (int tau = 0; tau < LSTM_WSTEPS; ++tau) {
    const int t = tau - 2;
    if (t >= 0 && t < 512) {
      f32x4 acc[4] = {{0,0,0,0},{0,0,0,0},{0,0,0,0},{0,0,0,0}};
      // h1_{t-1} at slot t (cached, virgin-fresh)
      const unsigned short* a2base =
          own + (size_t)t * (64 * 1152) + (size_t)(m0 + r) * 1152 + q * 8;
      f16x8 a2r[9];
#pragma unroll
      for (int i = 0; i < 9; ++i) a2r[i] = *(const f16x8*)(a2base + (kq + 4 * i) * 32);
      // IH partial (parity-2 reuse => MUST stay on the sc bypass path)
      f32x4 pl = load_sc128f(p.part + ((size_t)((t & 1) * 72 + g) * 1024 + tid) * 4);
      wait_vm0();
#pragma unroll
      for (int i = 0; i < 9; ++i) {
        int kb = kq + 4 * i;
        f16x8 a = a2r[i];
#pragma unroll
        for (int s2 = 0; s2 < 4; ++s2) {
          f16x8 b = *(const f16x8*)&ldsW[((s2 * 36 + kb) * 64 + lane) * 8];
          acc[s2] = __builtin_amdgcn_mfma_f32_16x16x32_f16(a, b, acc[s2], 0, 0, 0);
        }
      }
#pragma unroll
      for (int s2 = 0; s2 < 4; ++s2)
#pragma unroll
        for (int i = 0; i < 4; ++i)
          atomicAdd(&gates[s2 * 1024 + (m0 + q * 4 + i) * 16 + r], acc[s2][i]);
      __syncthreads();

      float pg[4];
#pragma unroll
      for (int s2 = 0; s2 < 4; ++s2) {
        pg[s2] = gates[s2 * 1024 + tid];
        gates[s2 * 1024 + tid] = 0.0f;
      }
      float ig = sigm_(pg[0] + pl[0] + bias4[0]);
      float fg = sigm_(pg[1] + pl[1] + bias4[1]);
      float gg = tanh_(pg[2] + pl[2] + bias4[2]);
      float og = sigm_(pg[3] + pl[3] + bias4[3]);
      c_val = fg * c_val + ig * gg;
      float h = og * tanh_(c_val);
      if (jglob >= 1150) h = 0.0f;

      unsigned v0  = (unsigned)f2h(h);
      unsigned o1  = __shfl_down(v0, 1);
      unsigned p01 = v0 | (o1 << 16);
      unsigned o2  = __shfl_down(p01, 2);
      unsigned o4a = __shfl_down(p01, 4);
      unsigned o4b = __shfl_down(o2, 4);
      if ((lane & 7) == 0) {
        u32x4 pk2; pk2[0] = p01; pk2[1] = o2; pk2[2] = o4a; pk2[3] = o4b;
        store_sc128(own + ((size_t)(t + 1) * 64 + b_) * 1152 + jglob, pk2);
      }
    }
    grid_barrier(p.bar, bid, tid, tau + 1);
  }
}

__global__ void __launch_bounds__(1024) lstm_persistent(KParams p) {
  extern __shared__ unsigned short smem[];
  unsigned short* ldsW = smem;
  float* gates = (float*)(smem + LDS_W_HALFS);
  const int bid = blockIdx.x;
  if (bid < 72)       run_layer<0, 0>(p, bid, bid, ldsW, gates);
  else if (bid < 144) run_l1_ih(p, bid - 72, bid, ldsW, gates);
  else if (bid < 216) run_l1_hh(p, bid - 144, bid, ldsW, gates);
  else                run_layer<2, 3>(p, bid - 216, bid, ldsW, gates);
}

// --- prep: fp32 [4*Jext][K] -> fp16 fragment-major [g][(s*NKB+kb)*64+lane][8] ---
__global__ void prep_weights(const float* __restrict__ src,
                             unsigned short* __restrict__ dst,
                             int Jext, int jg, int K, int NKB) {
  const int n = jg * 4 * NKB * 512;
  for (int idx = blockIdx.x * blockDim.x + threadIdx.x; idx < n;
       idx += gridDim.x * blockDim.x) {
    int e = idx & 7;
    int t2 = idx >> 3;
    int ln = t2 & 63; t2 >>= 6;
    int kb = t2 % NKB; t2 /= NKB;
    int s = t2 & 3;
    int g = t2 >> 2;
    int j = g * 16 + (ln & 15);
    int k = kb * 32 + (ln >> 4) * 8 + e;
    unsigned short v = 0;
    if (j < Jext && k < K) v = f2h(src[(size_t)(s * Jext + j) * K + k]);
    dst[idx] = v;
  }
}

__global__ void prep_bias(const float* __restrict__ bih,
                          const float* __restrict__ bhh,
                          float* __restrict__ dst, int Dh) {
  const int n = 4 * 1152;
  for (int idx = blockIdx.x * blockDim.x + threadIdx.x; idx < n;
       idx += gridDim.x * blockDim.x) {
    int s = idx / 1152, j = idx % 1152;
    float v = 0.0f;
    if (j < Dh) v = bih[s * Dh + j] + bhh[s * Dh + j];
    dst[idx] = v;
  }
}

// gather emb[tokens] (fp32) into padded fp16 [512*64][416] (cols 400..415 = 0)
__global__ void prep_gather(const int* __restrict__ tokens,
                            const float* __restrict__ emb,
                            unsigned short* __restrict__ xin0) {
  const int n = 512 * 64 * 52;
  for (int idx = blockIdx.x * blockDim.x + threadIdx.x; idx < n;
       idx += gridDim.x * blockDim.x) {
    int row = idx / 52;
    int cp  = idx - row * 52;
    unsigned short v[8] = {0, 0, 0, 0, 0, 0, 0, 0};
    if (cp < 50) {
      const float* src = emb + (size_t)tokens[row] * 400 + cp * 8;
      float4 a = *(const float4*)(src);
      float4 b = *(const float4*)(src + 4);
      v[0] = f2h(a.x); v[1] = f2h(a.y); v[2] = f2h(a.z); v[3] = f2h(a.w);
      v[4] = f2h(b.x); v[5] = f2h(b.y); v[6] = f2h(b.z); v[7] = f2h(b.w);
    }
    *(uint4*)(xin0 + (size_t)row * 416 + cp * 8) = *(const uint4*)v;
  }
}

extern "C" void kernel_launch(void* const* d_in, const int* in_sizes, int n_in,
                              void* d_out, int out_size, void* d_ws, size_t ws_size,
                              hipStream_t stream) {
  const int*   tokens = (const int*)d_in[0];
  const float* emb  = (const float*)d_in[1];
  const float* Wih0 = (const float*)d_in[2];
  const float* Whh0 = (const float*)d_in[3];
  const float* bih0 = (const float*)d_in[4];
  const float* bhh0 = (const float*)d_in[5];
  const float* Wih1 = (const float*)d_in[8];
  const float* Whh1 = (const float*)d_in[9];
  const float* bih1 = (const float*)d_in[10];
  const float* bhh1 = (const float*)d_in[11];
  const float* Wih2 = (const float*)d_in[14];
  const float* Whh2 = (const float*)d_in[15];
  const float* bih2 = (const float*)d_in[16];
  const float* bhh2 = (const float*)d_in[17];

  char* ws = (char*)d_ws;
  size_t off = 0;
  auto alloc = [&](size_t bytes) -> char* {
    char* ptr = ws + off;
    off += (bytes + 255) & ~(size_t)255;
    return ptr;
  };
  unsigned short* res0  = (unsigned short*)alloc(72ull * 4 * 36 * 512 * 2);
  unsigned short* res1  = (unsigned short*)alloc(72ull * 4 * 36 * 512 * 2);
  unsigned short* res2  = (unsigned short*)alloc(25ull * 4 * 36 * 512 * 2);
  unsigned short* strm0 = (unsigned short*)alloc(72ull * 4 * 13 * 512 * 2);
  unsigned short* strm1 = (unsigned short*)alloc(72ull * 4 * 36 * 512 * 2);
  unsigned short* strm2 = (unsigned short*)alloc(25ull * 4 * 13 * 512 * 2);
  float* bias0 = (float*)alloc(4ull * 1152 * 4);
  float* bias1 = (float*)alloc(4ull * 1152 * 4);
  float* bias2 = (float*)alloc(4ull * 1152 * 4);
  unsigned short* xin0  = (unsigned short*)alloc(512ull * 64 * 416 * 2);
  unsigned short* hseq0 = (unsigned short*)alloc(513ull * 64 * 1152 * 2); // 75.6 MB
  unsigned short* hseq1 = (unsigned short*)alloc(513ull * 64 * 1152 * 2); // 75.6 MB
  unsigned short* hseq2 = (unsigned short*)alloc(513ull * 64 * 416 * 2);  // 27.3 MB
  float* part = (float*)alloc(2ull * 72 * 1024 * 4 * 4);        // 2.36 MB
  int* bar = (int*)alloc((GO_BASE + 8) * 32 * 4);   // arrive[241]+go[8], 128B lines
  if (off > ws_size) return;

  hipLaunchKernelGGL(prep_gather, dim3(2048), dim3(256), 0, stream, tokens, emb, xin0);
  hipLaunchKernelGGL(prep_weights, dim3(4096), dim3(256), 0, stream, Whh0, res0, 1150, 72, 1150, 36);
  hipLaunchKernelGGL(prep_weights, dim3(4096), dim3(256), 0, stream, Whh1, res1, 1150, 72, 1150, 36);
  hipLaunchKernelGGL(prep_weights, dim3(4096), dim3(256), 0, stream, Wih2, res2, 400, 25, 1150, 36);
  hipLaunchKernelGGL(prep_weights, dim3(4096), dim3(256), 0, stream, Wih0, strm0, 1150, 72, 400, 13);
  hipLaunchKernelGGL(prep_weights, dim3(4096), dim3(256), 0, stream, Wih1, strm1, 1150, 72, 1150, 36);
  hipLaunchKernelGGL(prep_weights, dim3(4096), dim3(256), 0, stream, Whh2, strm2, 400, 25, 400, 13);
  hipLaunchKernelGGL(prep_bias, dim3(8), dim3(256), 0, stream, bih0, bhh0, bias0, 1150);
  hipLaunchKernelGGL(prep_bias, dim3(8), dim3(256), 0, stream, bih1, bhh1, bias1, 1150);
  hipLaunchKernelGGL(prep_bias, dim3(8), dim3(256), 0, stream, bih2, bhh2, bias2, 400);
  // Only slot 0 (h_{-1} = 0) needs zeroing; all other slots are write-before-read.
  (void)hipMemsetAsync(hseq0, 0, 64ull * 1152 * 2, stream);
  (void)hipMemsetAsync(hseq1, 0, 64ull * 1152 * 2, stream);
  (void)hipMemsetAsync(hseq2, 0, 64ull * 416 * 2, stream);
  (void)hipMemsetAsync(bar, 0, (GO_BASE + 8) * 32 * 4, stream);

  KParams kp;
  kp.res[0] = res0;  kp.res[1] = res1;  kp.res[2] = res2;
  kp.strm[0] = strm0; kp.strm[1] = strm1; kp.strm[2] = strm2;
  kp.bias[0] = bias0; kp.bias[1] = bias1; kp.bias[2] = bias2;
  kp.xin0 = xin0;
  kp.hseq[0] = hseq0; kp.hseq[1] = hseq1; kp.hseq[2] = hseq2;
  kp.part = part;
  kp.out = (float*)d_out;
  kp.bar = bar;

  (void)hipFuncSetAttribute((const void*)lstm_persistent,
                            hipFuncAttributeMaxDynamicSharedMemorySize,
                            LDS_TOTAL_BYTES);
  hipLaunchKernelGGL(lstm_persistent, dim3(LSTM_NBLK), dim3(1024),
                     LDS_TOTAL_BYTES, stream, kp);
}